// Round 1
// baseline (351.038 us; speedup 1.0000x reference)
//
#include <hip/hip_runtime.h>
#include <hip/hip_fp16.h>

typedef _Float16 f16x8 __attribute__((ext_vector_type(8)));
typedef _Float16 f16x4 __attribute__((ext_vector_type(4)));
typedef _Float16 f16x2 __attribute__((ext_vector_type(2)));
typedef float    f32x16 __attribute__((ext_vector_type(16)));
typedef float    f32x4 __attribute__((ext_vector_type(4)));

struct LayerPtrs {
  const float* w[8];
  const float* b[8];
};

// Weight fragments in d_ws, A-operand layout for mfma_f32_32x32x16_f16:
//   m = mtile*32 + (lane&31), k = kc*16 + (lane>>5)*8 + j ; value = W[k][m]
// index = WOFF[l] + (kc*8 + mtile)*64 + lane, element j.   (unchanged layout)
__global__ void prep_weights(LayerPtrs P, f16x8* __restrict__ wf) {
  int gid = blockIdx.x * 256 + threadIdx.x;
  if (gid >= 60416) return;
  const int OFF[9] = {0,1536,9728,17920,26112,35840,44032,52224,60416};
  int l = 0;
  while (gid >= OFF[l+1]) ++l;
  int f = gid - OFF[l];
  int lane = f & 63;
  int t = f >> 6;
  int mtile = t & 7;
  int kc = t >> 3;
  int col = mtile * 32 + (lane & 31);
  int kb  = (lane >> 5) * 8;
  const float* w = P.w[l];
  f16x8 v;
#pragma unroll
  for (int j = 0; j < 8; ++j) {
    float x = 0.f;
    if (l == 4) {
      if (kc < 3) {
        int k = kc * 16 + kb + j;
        if (k < 39) x = w[k * 256 + col];
      } else {
        int k = (kc - 3) * 16 + kb + j;
        x = w[(39 + k) * 256 + col];
      }
    } else if (l == 0) {
      int k = kc * 16 + kb + j;
      if (k < 39) x = w[k * 256 + col];
    } else {
      int k = kc * 16 + kb + j;
      x = w[k * 256 + col];
    }
    v[j] = (_Float16)x;
  }
  wf[gid] = v;
}

#define MFMA __builtin_amdgcn_mfma_f32_32x32x16_f16

// kc0 + kc1 weight frags for one wave's 2 m-tiles (2-deep prefetch seed).
struct WPre2 { f16x8 a00, a01, a10, a11; };

__device__ __forceinline__ WPre2 wpre2(const f16x8* __restrict__ wb) {
  WPre2 p;
  p.a00 = wb[0];   p.a01 = wb[64];    // kc0: mt0, mt1
  p.a10 = wb[512]; p.a11 = wb[576];   // kc1: mt0, mt1
  return p;
}

// Wave = 64 hidden (2 mt) x 64 points (2 nt): 4 MFMA per kc.
// A (weights, global/L2) pipelined 2 kc ahead; B (activations, LDS) 1 ahead.
// Activation rows are XOR-swizzled: physical byte = logical ^ xr, xr=(p0&7)<<4.
// FIRST: kc0 uses a zero C operand (bias is added in the epilogue).
template<int NKC, bool FIRST, int RSTRIDE, bool PRE>
__device__ __forceinline__ void mm(const f16x8* __restrict__ wb,
                                   const char* __restrict__ r0,
                                   int col0, int xr,
                                   f32x16 acc[2][2], WPre2 wp) {
  f16x8 a00, a01, a10, a11;
  if (PRE) { a00 = wp.a00; a01 = wp.a01; a10 = wp.a10; a11 = wp.a11; }
  else     { a00 = wb[0];  a01 = wb[64]; a10 = wb[512]; a11 = wb[576]; }
  int off0 = col0 ^ xr;
  f16x8 v0 = *(const f16x8*)(r0 + off0);
  f16x8 v1 = *(const f16x8*)(r0 + RSTRIDE + off0);
#pragma unroll
  for (int kc = 0; kc < NKC; ++kc) {
    f16x8 n0, n1, nv0, nv1;
    if (kc + 2 < NKC) {
      n0 = wb[(kc + 2) * 512];
      n1 = wb[(kc + 2) * 512 + 64];
    }
    if (kc + 1 < NKC) {
      int off = (col0 + 32 * (kc + 1)) ^ xr;
      nv0 = *(const f16x8*)(r0 + off);
      nv1 = *(const f16x8*)(r0 + RSTRIDE + off);
    }
    if (FIRST && kc == 0) {
      const f32x16 z = {};
      acc[0][0] = MFMA(a00, v0, z, 0, 0, 0);
      acc[0][1] = MFMA(a00, v1, z, 0, 0, 0);
      acc[1][0] = MFMA(a01, v0, z, 0, 0, 0);
      acc[1][1] = MFMA(a01, v1, z, 0, 0, 0);
    } else {
      acc[0][0] = MFMA(a00, v0, acc[0][0], 0, 0, 0);
      acc[0][1] = MFMA(a00, v1, acc[0][1], 0, 0, 0);
      acc[1][0] = MFMA(a01, v0, acc[1][0], 0, 0, 0);
      acc[1][1] = MFMA(a01, v1, acc[1][1], 0, 0, 0);
    }
    a00 = a10; a01 = a11; a10 = n0; a11 = n1;
    v0 = nv0; v1 = nv1;
  }
}

__device__ __forceinline__ f16x4 relu_cvt4(float a0, float a1, float a2, float a3) {
  f16x2 lo = __builtin_bit_cast(f16x2, __builtin_amdgcn_cvt_pkrtz(a0, a1));
  f16x2 hi = __builtin_bit_cast(f16x2, __builtin_amdgcn_cvt_pkrtz(a2, a3));
  union { f16x4 v; f16x2 h[2]; } u;
  u.h[0] = lo; u.h[1] = hi;
  f16x4 z = {};
  return __builtin_elementwise_max(u.v, z);
}

// C/D 32x32: col(point) = lane&31, row(hidden) = (reg&3) + 8*(reg>>2) + 4*(lane>>5)
// Epilogue adds bias (acc + b) before relu, then f16x4 store, XOR-swizzled.
__device__ __forceinline__ void store_epi(f32x16 acc[2][2],
                                          const float* __restrict__ bias,
                                          int wg_h, int wg_p, int p0, int h,
                                          int xr, _Float16* __restrict__ Hs) {
  char* base = (char*)Hs + (wg_p * 64 + p0) * 512;
#pragma unroll
  for (int mt = 0; mt < 2; ++mt) {
#pragma unroll
    for (int g = 0; g < 4; ++g) {
      f32x4 q = *(const f32x4*)&bias[wg_h * 64 + mt * 32 + 8 * g + 4 * h];
      int bc = (128 * wg_h + 64 * mt + 8 * h + 16 * g) ^ xr;
#pragma unroll
      for (int nt = 0; nt < 2; ++nt) {
        f16x4 o = relu_cvt4(acc[mt][nt][4 * g + 0] + q[0],
                            acc[mt][nt][4 * g + 1] + q[1],
                            acc[mt][nt][4 * g + 2] + q[2],
                            acc[mt][nt][4 * g + 3] + q[3]);
        *(f16x4*)(base + nt * 32 * 512 + bc) = o;
      }
    }
  }
}

// 512 threads = 8 waves: wg_h = wave&3 (hidden 64-slice), wg_p = wave>>2
// (points 64-slice). LDS: H 128x256 f16 (64KB, swizzled) + E 128x64 f16 (16KB)
// = 81920 B -> 2 blocks/CU; VGPR target 128 -> 4 waves/SIMD.
__global__ __launch_bounds__(512, 4)
void mlp_fused(const float* __restrict__ points,
               LayerPtrs P,
               const f16x8* __restrict__ wf,
               const float* __restrict__ wsdf,
               const float* __restrict__ bsdf,
               float* __restrict__ out) {
  __shared__ __align__(16) _Float16 Hs[128 * 256];   // 65536 B
  __shared__ __align__(16) _Float16 Es[128 * 64];    // 16384 B
  const int tid = threadIdx.x;
  const int blk = blockIdx.x;

  const int lane = tid & 63;
  const int w    = tid >> 6;
  const int wg_h = w & 3;
  const int wg_p = w >> 2;
  const int p0   = lane & 31;
  const int h    = lane >> 5;
  const int xr   = (p0 & 7) << 4;
  const int col0 = 16 * h;

  const f16x8* wb = wf + wg_h * 128 + lane;   // + WOFF[l] + kc*512 (+64 for mt1)

  // L0 kc0/kc1 weights in flight before the embedding VALU phase.
  WPre2 wp = wpre2(wb);

  // ---- embedding: 4 threads/point. part 0..2 -> channel c; part 3 -> zero pad.
  // E logical cols: [sin(18) | cos(18) | xyz(3) | zeros 39..47]; row = point.
  {
    int p = tid & 127, part = tid >> 7;
    char* Erow = (char*)Es + p * 128;
    int xp = (p & 7) << 4;
    if (part < 3) {
      float x = points[(blk * 128 + p) * 3 + part];
      _Float16 sv[6], cv[6];
      float fr = 1.f;
#pragma unroll
      for (int k = 0; k < 6; ++k) {
        float e = x * fr;
        sv[k] = (_Float16)__sinf(e);
        cv[k] = (_Float16)__cosf(e);
        fr *= 2.f;
      }
#pragma unroll
      for (int k = 0; k < 6; k += 2) {
        f16x2 s2 = {sv[k], sv[k + 1]};
        f16x2 c2 = {cv[k], cv[k + 1]};
        *(f16x2*)(Erow + ((2 * (6 * part + k)) ^ xp)) = s2;
        *(f16x2*)(Erow + ((2 * (18 + 6 * part + k)) ^ xp)) = c2;
      }
      *(_Float16*)(Erow + ((2 * (36 + part)) ^ xp)) = (_Float16)x;
    } else {
      f16x4 z4 = {};
      *(_Float16*)(Erow + (78 ^ xp)) = (_Float16)0.f;   // col 39
      *(f16x4*)(Erow + (80 ^ xp)) = z4;                 // cols 40..43
      *(f16x4*)(Erow + (88 ^ xp)) = z4;                 // cols 44..47
    }
  }
  __syncthreads();

  const char* hR = (const char*)Hs + (wg_p * 64 + p0) * 512;
  const char* eR = (const char*)Es + (wg_p * 64 + p0) * 128;

  f32x16 acc[2][2];

  // L0: read E, write H (disjoint -> no barrier between mm and store)
  mm<3, true, 4096, true>(wb, eR, col0, xr, acc, wp);
  wp = wpre2(wb + 1536);
  store_epi(acc, P.b[0], wg_h, wg_p, p0, h, xr, Hs);
  __syncthreads();

  const int WOFF[8] = {0, 1536, 9728, 17920, 26112, 35840, 44032, 52224};

  // L1..L3: in-place H
#pragma unroll
  for (int l = 1; l < 4; ++l) {
    mm<16, true, 16384, true>(wb + WOFF[l], hR, col0, xr, acc, wp);
    wp = wpre2(wb + WOFF[l + 1]);
    __syncthreads();
    store_epi(acc, P.b[l], wg_h, wg_p, p0, h, xr, Hs);
    __syncthreads();
  }

  // L4: concat input = E (3 kc, zero-C) + H (16 kc, accumulate, non-prefetched A)
  {
    mm<3, true, 4096, true>(wb + 26112, eR, col0, xr, acc, wp);
    mm<16, false, 16384, false>(wb + 27648, hR, col0, xr, acc, wp);
    wp = wpre2(wb + 35840);
    __syncthreads();
    store_epi(acc, P.b[4], wg_h, wg_p, p0, h, xr, Hs);
    __syncthreads();
  }

  // L5..L6
#pragma unroll
  for (int l = 5; l < 7; ++l) {
    mm<16, true, 16384, true>(wb + WOFF[l], hR, col0, xr, acc, wp);
    wp = wpre2(wb + WOFF[l + 1]);
    __syncthreads();
    store_epi(acc, P.b[l], wg_h, wg_p, p0, h, xr, Hs);
    __syncthreads();
  }

  // L7 + SDF head: out[p] = sum_h relu(x7 + b7)[p][h] * wsdf[h] + bsdf
  mm<16, true, 16384, true>(wb + 52224, hR, col0, xr, acc, wp);
  {
    float part0 = 0.f, part1 = 0.f;
    const float* b7 = P.b[7];
#pragma unroll
    for (int mt = 0; mt < 2; ++mt) {
#pragma unroll
      for (int g = 0; g < 4; ++g) {
        int idx = wg_h * 64 + mt * 32 + 8 * g + 4 * h;
        f32x4 qb = *(const f32x4*)&b7[idx];
        f32x4 qw = *(const f32x4*)&wsdf[idx];
#pragma unroll
        for (int r = 0; r < 4; ++r) {
          part0 += fmaxf(acc[mt][0][4 * g + r] + qb[r], 0.f) * qw[r];
          part1 += fmaxf(acc[mt][1][4 * g + r] + qb[r], 0.f) * qw[r];
        }
      }
    }
    // E space dead since L4 (block-wide barriers since) -> partial buffer
    // PB[8][128] floats (4 KB). PB writes touch only Es; L7 reads only Hs.
    float* PB = (float*)Es;
    PB[(wg_h * 2 + h) * 128 + wg_p * 64 + p0]      = part0;
    PB[(wg_h * 2 + h) * 128 + wg_p * 64 + 32 + p0] = part1;
    __syncthreads();
    if (tid < 128) {
      float s = bsdf[0];
#pragma unroll
      for (int j = 0; j < 8; ++j) s += PB[j * 128 + tid];
      out[blk * 128 + tid] = s;
    }
  }
}

extern "C" void kernel_launch(void* const* d_in, const int* in_sizes, int n_in,
                              void* d_out, int out_size, void* d_ws, size_t ws_size,
                              hipStream_t stream) {
  const float* points = (const float*)d_in[0];
  LayerPtrs P;
  for (int i = 0; i < 8; ++i) {
    P.w[i] = (const float*)d_in[1 + 2 * i];
    P.b[i] = (const float*)d_in[2 + 2 * i];
  }
  const float* wsdf = (const float*)d_in[17];
  const float* bsdf = (const float*)d_in[18];
  f16x8* wf = (f16x8*)d_ws;   // needs 966656 B

  int N = in_sizes[0] / 3;    // 262144
  prep_weights<<<236, 256, 0, stream>>>(P, wf);
  mlp_fused<<<N / 128, 512, 0, stream>>>(points, P, wf, wsdf, bsdf, (float*)d_out);
}

// Round 2
// 327.584 us; speedup vs baseline: 1.0716x; 1.0716x over previous
//
#include <hip/hip_runtime.h>
#include <hip/hip_fp16.h>

typedef _Float16 f16x8 __attribute__((ext_vector_type(8)));
typedef _Float16 f16x4 __attribute__((ext_vector_type(4)));
typedef _Float16 f16x2 __attribute__((ext_vector_type(2)));
typedef float    f32x16 __attribute__((ext_vector_type(16)));
typedef float    f32x4 __attribute__((ext_vector_type(4)));

struct LayerPtrs {
  const float* w[8];
  const float* b[8];
};

// Weight fragments in d_ws, A-operand layout for mfma_f32_32x32x16_f16:
//   m = mtile*32 + (lane&31), k = kc*16 + (lane>>5)*8 + j ; value = W[k][m]
// index = WOFF[l] + (kc*8 + mtile)*64 + lane, element j.
__global__ void prep_weights(LayerPtrs P, f16x8* __restrict__ wf) {
  int gid = blockIdx.x * 256 + threadIdx.x;
  if (gid >= 60416) return;
  const int OFF[9] = {0,1536,9728,17920,26112,35840,44032,52224,60416};
  int l = 0;
  while (gid >= OFF[l+1]) ++l;
  int f = gid - OFF[l];
  int lane = f & 63;
  int t = f >> 6;
  int mtile = t & 7;
  int kc = t >> 3;
  int col = mtile * 32 + (lane & 31);
  int kb  = (lane >> 5) * 8;
  const float* w = P.w[l];
  f16x8 v;
#pragma unroll
  for (int j = 0; j < 8; ++j) {
    float x = 0.f;
    if (l == 4) {
      if (kc < 3) {
        int k = kc * 16 + kb + j;
        if (k < 39) x = w[k * 256 + col];
      } else {
        int k = (kc - 3) * 16 + kb + j;
        x = w[(39 + k) * 256 + col];
      }
    } else if (l == 0) {
      int k = kc * 16 + kb + j;
      if (k < 39) x = w[k * 256 + col];
    } else {
      int k = kc * 16 + kb + j;
      x = w[k * 256 + col];
    }
    v[j] = (_Float16)x;
  }
  wf[gid] = v;
}

#define MFMA __builtin_amdgcn_mfma_f32_32x32x16_f16

// Wave = 64 hidden (2 mt) x 64 points (2 nt): 4 MFMA per kc.
// In-loop pipeline only: A (weights, L2) depth-2; V (activations, LDS) depth-1.
// NOTHING is held live across barriers (round-1 lesson: cross-barrier
// prefetch registers caused scratch spills that made the kernel HBM-bound).
// Activation rows XOR-swizzled: physical byte = logical ^ xr, xr=(p0&7)<<4.
// FIRST: kc0 uses a zero C operand (bias is added in the epilogue).
template<int NKC, bool FIRST, int RSTRIDE>
__device__ __forceinline__ void mm(const f16x8* __restrict__ wb,
                                   const char* __restrict__ r0,
                                   int col0, int xr,
                                   f32x16 acc[2][2]) {
  f16x8 a0 = wb[0];
  f16x8 a1 = wb[64];
  f16x8 b0, b1;
  if (NKC > 1) { b0 = wb[512]; b1 = wb[576]; }
  int off0 = col0 ^ xr;
  f16x8 v0 = *(const f16x8*)(r0 + off0);
  f16x8 v1 = *(const f16x8*)(r0 + RSTRIDE + off0);
#pragma unroll
  for (int kc = 0; kc < NKC; ++kc) {
    f16x8 na0, na1, nv0, nv1;
    if (kc + 2 < NKC) {
      na0 = wb[(kc + 2) * 512];
      na1 = wb[(kc + 2) * 512 + 64];
    }
    if (kc + 1 < NKC) {
      int off = (col0 + 32 * (kc + 1)) ^ xr;
      nv0 = *(const f16x8*)(r0 + off);
      nv1 = *(const f16x8*)(r0 + RSTRIDE + off);
    }
    if (FIRST && kc == 0) {
      const f32x16 z = {};
      acc[0][0] = MFMA(a0, v0, z, 0, 0, 0);
      acc[0][1] = MFMA(a0, v1, z, 0, 0, 0);
      acc[1][0] = MFMA(a1, v0, z, 0, 0, 0);
      acc[1][1] = MFMA(a1, v1, z, 0, 0, 0);
    } else {
      acc[0][0] = MFMA(a0, v0, acc[0][0], 0, 0, 0);
      acc[0][1] = MFMA(a0, v1, acc[0][1], 0, 0, 0);
      acc[1][0] = MFMA(a1, v0, acc[1][0], 0, 0, 0);
      acc[1][1] = MFMA(a1, v1, acc[1][1], 0, 0, 0);
    }
    a0 = b0; a1 = b1; b0 = na0; b1 = na1;
    v0 = nv0; v1 = nv1;
  }
}

__device__ __forceinline__ f16x4 relu_cvt4(float a0, float a1, float a2, float a3) {
  f16x2 lo = __builtin_bit_cast(f16x2, __builtin_amdgcn_cvt_pkrtz(a0, a1));
  f16x2 hi = __builtin_bit_cast(f16x2, __builtin_amdgcn_cvt_pkrtz(a2, a3));
  union { f16x4 v; f16x2 h[2]; } u;
  u.h[0] = lo; u.h[1] = hi;
  f16x4 z = {};
  return __builtin_elementwise_max(u.v, z);
}

// C/D 32x32: col(point) = lane&31, row(hidden) = (reg&3) + 8*(reg>>2) + 4*(lane>>5)
// Epilogue adds bias (acc + b) before relu, then f16x4 store, XOR-swizzled.
__device__ __forceinline__ void store_epi(f32x16 acc[2][2],
                                          const float* __restrict__ bias,
                                          int wg_h, int wg_p, int p0, int h,
                                          int xr, _Float16* __restrict__ Hs) {
  char* base = (char*)Hs + (wg_p * 64 + p0) * 512;
#pragma unroll
  for (int mt = 0; mt < 2; ++mt) {
#pragma unroll
    for (int g = 0; g < 4; ++g) {
      f32x4 q = *(const f32x4*)&bias[wg_h * 64 + mt * 32 + 8 * g + 4 * h];
      int bc = (128 * wg_h + 64 * mt + 8 * h + 16 * g) ^ xr;
#pragma unroll
      for (int nt = 0; nt < 2; ++nt) {
        f16x4 o = relu_cvt4(acc[mt][nt][4 * g + 0] + q[0],
                            acc[mt][nt][4 * g + 1] + q[1],
                            acc[mt][nt][4 * g + 2] + q[2],
                            acc[mt][nt][4 * g + 3] + q[3]);
        *(f16x4*)(base + nt * 32 * 512 + bc) = o;
      }
    }
  }
}

// 512 threads = 8 waves: wg_h = wave&3 (hidden 64-slice), wg_p = wave>>2
// (points 64-slice). LDS: H 128x256 f16 (64KB, swizzled) + E 128x64 f16 (16KB)
// = 81920 B -> 2 blocks/CU; target 4 waves/SIMD.
__global__ __launch_bounds__(512, 4)
void mlp_fused(const float* __restrict__ points,
               LayerPtrs P,
               const f16x8* __restrict__ wf,
               const float* __restrict__ wsdf,
               const float* __restrict__ bsdf,
               float* __restrict__ out) {
  __shared__ __align__(16) _Float16 Hs[128 * 256];   // 65536 B
  __shared__ __align__(16) _Float16 Es[128 * 64];    // 16384 B
  const int tid = threadIdx.x;
  const int blk = blockIdx.x;

  const int lane = tid & 63;
  const int w    = tid >> 6;
  const int wg_h = w & 3;
  const int wg_p = w >> 2;
  const int p0   = lane & 31;
  const int h    = lane >> 5;
  const int xr   = (p0 & 7) << 4;
  const int col0 = 16 * h;

  const f16x8* wb = wf + wg_h * 128 + lane;   // + WOFF[l] + kc*512 (+64 for mt1)

  // ---- embedding: 4 threads/point. part 0..2 -> channel c; part 3 -> zero pad.
  // E logical cols: [sin(18) | cos(18) | xyz(3) | zeros 39..47]; row = point.
  {
    int p = tid & 127, part = tid >> 7;
    char* Erow = (char*)Es + p * 128;
    int xp = (p & 7) << 4;
    if (part < 3) {
      float x = points[(blk * 128 + p) * 3 + part];
      _Float16 sv[6], cv[6];
      float fr = 1.f;
#pragma unroll
      for (int k = 0; k < 6; ++k) {
        float e = x * fr;
        sv[k] = (_Float16)__sinf(e);
        cv[k] = (_Float16)__cosf(e);
        fr *= 2.f;
      }
#pragma unroll
      for (int k = 0; k < 6; k += 2) {
        f16x2 s2 = {sv[k], sv[k + 1]};
        f16x2 c2 = {cv[k], cv[k + 1]};
        *(f16x2*)(Erow + ((2 * (6 * part + k)) ^ xp)) = s2;
        *(f16x2*)(Erow + ((2 * (18 + 6 * part + k)) ^ xp)) = c2;
      }
      *(_Float16*)(Erow + ((2 * (36 + part)) ^ xp)) = (_Float16)x;
    } else {
      f16x4 z4 = {};
      *(_Float16*)(Erow + (78 ^ xp)) = (_Float16)0.f;   // col 39
      *(f16x4*)(Erow + (80 ^ xp)) = z4;                 // cols 40..43
      *(f16x4*)(Erow + (88 ^ xp)) = z4;                 // cols 44..47
    }
  }
  __syncthreads();

  const char* hR = (const char*)Hs + (wg_p * 64 + p0) * 512;
  const char* eR = (const char*)Es + (wg_p * 64 + p0) * 128;

  f32x16 acc[2][2];

  // L0: read E, write H (disjoint -> no barrier between mm and store)
  mm<3, true, 4096>(wb, eR, col0, xr, acc);
  store_epi(acc, P.b[0], wg_h, wg_p, p0, h, xr, Hs);
  __syncthreads();

  const int WOFF[8] = {0, 1536, 9728, 17920, 26112, 35840, 44032, 52224};

  // L1..L3: in-place H
#pragma unroll
  for (int l = 1; l < 4; ++l) {
    mm<16, true, 16384>(wb + WOFF[l], hR, col0, xr, acc);
    __syncthreads();
    store_epi(acc, P.b[l], wg_h, wg_p, p0, h, xr, Hs);
    __syncthreads();
  }

  // L4: concat input = E (3 kc, zero-C) + H (16 kc, accumulate)
  {
    mm<3, true, 4096>(wb + 26112, eR, col0, xr, acc);
    mm<16, false, 16384>(wb + 27648, hR, col0, xr, acc);
    __syncthreads();
    store_epi(acc, P.b[4], wg_h, wg_p, p0, h, xr, Hs);
    __syncthreads();
  }

  // L5..L6
#pragma unroll
  for (int l = 5; l < 7; ++l) {
    mm<16, true, 16384>(wb + WOFF[l], hR, col0, xr, acc);
    __syncthreads();
    store_epi(acc, P.b[l], wg_h, wg_p, p0, h, xr, Hs);
    __syncthreads();
  }

  // L7 + SDF head: out[p] = sum_h relu(x7 + b7)[p][h] * wsdf[h] + bsdf
  mm<16, true, 16384>(wb + 52224, hR, col0, xr, acc);
  {
    float part0 = 0.f, part1 = 0.f;
    const float* b7 = P.b[7];
#pragma unroll
    for (int mt = 0; mt < 2; ++mt) {
#pragma unroll
      for (int g = 0; g < 4; ++g) {
        int idx = wg_h * 64 + mt * 32 + 8 * g + 4 * h;
        f32x4 qb = *(const f32x4*)&b7[idx];
        f32x4 qw = *(const f32x4*)&wsdf[idx];
#pragma unroll
        for (int r = 0; r < 4; ++r) {
          part0 += fmaxf(acc[mt][0][4 * g + r] + qb[r], 0.f) * qw[r];
          part1 += fmaxf(acc[mt][1][4 * g + r] + qb[r], 0.f) * qw[r];
        }
      }
    }
    // E space dead since L4 (block-wide barriers since) -> partial buffer
    // PB[8][128] floats (4 KB). PB writes touch only Es; L7 reads only Hs.
    float* PB = (float*)Es;
    PB[(wg_h * 2 + h) * 128 + wg_p * 64 + p0]      = part0;
    PB[(wg_h * 2 + h) * 128 + wg_p * 64 + 32 + p0] = part1;
    __syncthreads();
    if (tid < 128) {
      float s = bsdf[0];
#pragma unroll
      for (int j = 0; j < 8; ++j) s += PB[j * 128 + tid];
      out[blk * 128 + tid] = s;
    }
  }
}

extern "C" void kernel_launch(void* const* d_in, const int* in_sizes, int n_in,
                              void* d_out, int out_size, void* d_ws, size_t ws_size,
                              hipStream_t stream) {
  const float* points = (const float*)d_in[0];
  LayerPtrs P;
  for (int i = 0; i < 8; ++i) {
    P.w[i] = (const float*)d_in[1 + 2 * i];
    P.b[i] = (const float*)d_in[2 + 2 * i];
  }
  const float* wsdf = (const float*)d_in[17];
  const float* bsdf = (const float*)d_in[18];
  f16x8* wf = (f16x8*)d_ws;   // needs 966656 B

  int N = in_sizes[0] / 3;    // 262144
  prep_weights<<<236, 256, 0, stream>>>(P, wf);
  mlp_fused<<<N / 128, 512, 0, stream>>>(points, P, wf, wsdf, bsdf, (float*)d_out);
}